// Round 4
// baseline (461.616 us; speedup 1.0000x reference)
//
#include <hip/hip_runtime.h>

typedef __attribute__((ext_vector_type(8))) short short8;
typedef __attribute__((ext_vector_type(4))) float f32x4;

#define NNODES 55296
#define DOUT 256

__device__ __forceinline__ float bf2f(unsigned short h) {
    union { unsigned u; float f; } x; x.u = ((unsigned)h) << 16; return x.f;
}
__device__ __forceinline__ unsigned short f2bf(float f) {
    union { float f; unsigned u; } x; x.f = f;
    return (unsigned short)((x.u + 0x7fffu + ((x.u >> 16) & 1u)) >> 16);
}

__device__ __forceinline__ void storev(float* p, float v) { *p = v; }
__device__ __forceinline__ void storev(unsigned short* p, float v) { *p = f2bf(v); }

// ---- fragment helpers ----
__device__ __forceinline__ short8 frag_self(const float* p) {
    float4 a = *(const float4*)p, b = *(const float4*)(p + 4);
    union { short8 s; unsigned short u[8]; } r;
    r.u[0] = f2bf(a.x); r.u[1] = f2bf(a.y); r.u[2] = f2bf(a.z); r.u[3] = f2bf(a.w);
    r.u[4] = f2bf(b.x); r.u[5] = f2bf(b.y); r.u[6] = f2bf(b.z); r.u[7] = f2bf(b.w);
    return r.s;
}
__device__ __forceinline__ short8 frag_self(const unsigned short* p) {
    return *(const short8*)p;
}
__device__ __forceinline__ void acc8(const float* p, float* o) {
    float4 a = *(const float4*)p, b = *(const float4*)(p + 4);
    o[0] += a.x; o[1] += a.y; o[2] += a.z; o[3] += a.w;
    o[4] += b.x; o[5] += b.y; o[6] += b.z; o[7] += b.w;
}
__device__ __forceinline__ void acc8(const unsigned short* p, float* o) {
    uint4 v = *(const uint4*)p;
    const unsigned short* u = (const unsigned short*)&v;
#pragma unroll
    for (int i = 0; i < 8; ++i) o[i] += bf2f(u[i]);
}
template <typename TIN>
__device__ __forceinline__ short8 frag_mean4(const TIN* p0, const TIN* p1,
                                             const TIN* p2, const TIN* p3) {
    float s[8] = {0.f, 0.f, 0.f, 0.f, 0.f, 0.f, 0.f, 0.f};
    acc8(p0, s); acc8(p1, s); acc8(p2, s); acc8(p3, s);
    union { short8 s8; unsigned short u[8]; } r;
#pragma unroll
    for (int i = 0; i < 8; ++i) r.u[i] = f2bf(s[i] * 0.25f);
    return r.s8;
}

// Wt[d][k] = bf16( k < C ? W_self[k][d] : W_neigh[k-C][d] )
__global__ void build_wt(const float* __restrict__ Ws,
                         const float* __restrict__ Wn,
                         unsigned short* __restrict__ Wt, int C) {
    int K2 = 2 * C;
    int idx = blockIdx.x * 256 + threadIdx.x;
    if (idx >= 256 * K2) return;
    int d = idx / K2;
    int k = idx - d * K2;
    float v = (k < C) ? Ws[(size_t)k * DOUT + d] : Wn[(size_t)(k - C) * DOUT + d];
    Wt[idx] = f2bf(v);
}

// ---- precompute hm[node][c] = bf16(mean of 4 neighbors) ----
template <int C, typename TIN>
__global__ __launch_bounds__(256) void mean_pass(const TIN* __restrict__ hin,
                                                 const int* __restrict__ nbr,
                                                 unsigned short* __restrict__ hm) {
    constexpr int CPL = C / 8;  // 8-ch chunks per node (16 or 32)
    const int idx = blockIdx.x * 256 + threadIdx.x;
    const int node = idx / CPL;
    const int ch = (idx - node * CPL) * 8;
    const int b = node / NNODES;
    const int n = node - b * NNODES;
    const size_t bbase = (size_t)b * NNODES;
    const int4 nb = *(const int4*)(nbr + (size_t)n * 4);
    float s[8] = {0.f, 0.f, 0.f, 0.f, 0.f, 0.f, 0.f, 0.f};
    acc8(hin + (bbase + nb.x) * (size_t)C + ch, s);
    acc8(hin + (bbase + nb.y) * (size_t)C + ch, s);
    acc8(hin + (bbase + nb.z) * (size_t)C + ch, s);
    acc8(hin + (bbase + nb.w) * (size_t)C + ch, s);
    union { uint4 v; unsigned short u[8]; } r;
#pragma unroll
    for (int i = 0; i < 8; ++i) r.u[i] = f2bf(s[i] * 0.25f);
    *(uint4*)(hm + (size_t)node * C + ch) = r.v;
}

// ---- v4: dense GEMM, weights in 64KB static LDS (2 blocks/CU), A = two linear
// streams (self | precomputed mean). Wave tile 64 rows x 64 cols. ----
template <int C, typename TIN, typename TOUT>
__global__ __launch_bounds__(512, 4) void sage_v4(
    const TIN* __restrict__ hin,              // [M][C]
    const unsigned short* __restrict__ hm,    // [M][C] bf16
    const unsigned short* __restrict__ Wt,    // [256][2C] bf16, d-major
    const float* __restrict__ bias,           // [256]
    TOUT* __restrict__ out) {                 // [M][256]
    constexpr int K2 = 2 * C;
    constexpr int ROWB = K2 * 2;              // bytes per Wt row
    constexpr int LCOLS = 65536 / ROWB;       // 128 (L1) / 64 (L2)
    constexpr int CG = LCOLS / 64;            // wave col-groups: 2 / 1
    constexpr int RG = 8 / CG;                // wave row-groups: 4 / 8
    __shared__ __align__(16) char Bs[65536];

    const int tid = threadIdx.x;
    const int gcol0 = blockIdx.y * LCOLS;

    // stage weights (64KB), XOR-swizzled by (col&7)<<4
    {
        const char* src = (const char*)(Wt + (size_t)gcol0 * K2);
#pragma unroll
        for (int i = 0; i < 8; ++i) {
            int byt = (i * 512 + tid) * 16;
            uint4 v = *(const uint4*)(src + byt);
            int c = byt / ROWB;
            *(uint4*)(Bs + (byt ^ ((c & 7) << 4))) = v;
        }
    }
    __syncthreads();

    const int l = tid & 63;
    const int w = tid >> 6;
    const int rowg = w / CG;
    const int colb = (w % CG) * 64;
    const int lr = l & 15, lg = l >> 4;

    const int rowbase = blockIdx.x * (RG * 64) + rowg * 64;
    const char* hb = (const char*)hin;
    const char* hmb = (const char*)hm;

    unsigned sofs[4], mofs[4];
#pragma unroll
    for (int m = 0; m < 4; ++m) {
        const int r = rowbase + m * 16 + lr;
        sofs[m] = (unsigned)(((size_t)r * C + lg * 8) * sizeof(TIN));
        mofs[m] = (unsigned)(((size_t)r * C + lg * 8) * 2);
    }

    f32x4 acc[4][4];
#pragma unroll
    for (int m = 0; m < 4; ++m)
#pragma unroll
        for (int j = 0; j < 4; ++j) acc[m][j] = (f32x4){0.f, 0.f, 0.f, 0.f};

#pragma unroll
    for (int kk = 0; kk < K2 / 32; ++kk) {
        const int k0 = kk * 32;
        short8 a[4];
        if (k0 < C) {
#pragma unroll
            for (int m = 0; m < 4; ++m)
                a[m] = frag_self((const TIN*)(hb + sofs[m] + (size_t)k0 * sizeof(TIN)));
        } else {
#pragma unroll
            for (int m = 0; m < 4; ++m)
                a[m] = *(const short8*)(hmb + mofs[m] + (size_t)(k0 - C) * 2);
        }
#pragma unroll
        for (int j = 0; j < 4; ++j) {
            const int c = colb + j * 16 + lr;
            const short8 bf = *(const short8*)(
                Bs + ((c * ROWB + (k0 + lg * 8) * 2) ^ ((l & 7) << 4)));
#pragma unroll
            for (int m = 0; m < 4; ++m)
                acc[m][j] = __builtin_amdgcn_mfma_f32_16x16x32_bf16(a[m], bf, acc[m][j], 0, 0, 0);
        }
    }

#pragma unroll
    for (int j = 0; j < 4; ++j) {
        const int gcol = gcol0 + colb + j * 16 + lr;
        const float bv = bias[gcol];
#pragma unroll
        for (int m = 0; m < 4; ++m) {
#pragma unroll
            for (int r = 0; r < 4; ++r) {
                const int row = rowbase + m * 16 + lg * 4 + r;
                storev(out + (size_t)row * DOUT + gcol, fmaxf(acc[m][j][r] + bv, 0.f));
            }
        }
    }
}

// ---- v3 (round-3 kernel), kept as fallback when ws is too small ----
template <int C, typename TIN, typename TOUT>
__global__ __launch_bounds__(512, 2) void sage_v3(
    const TIN* __restrict__ hin, const int* __restrict__ nbr,
    const unsigned short* __restrict__ Wt, const float* __restrict__ bias,
    TOUT* __restrict__ out) {
    constexpr int K2 = 2 * C;
    constexpr int ROWB = K2 * 2;
    constexpr int LCOLS = 131072 / ROWB;
    constexpr int CG = LCOLS / 128;
    constexpr int RG = 8 / CG;
    extern __shared__ char Bs[];

    const int tid = threadIdx.x;
    const int gcol0 = blockIdx.y * LCOLS;
    {
        const char* src = (const char*)(Wt + (size_t)gcol0 * K2);
#pragma unroll
        for (int i = 0; i < 131072 / (512 * 16); ++i) {
            int byt = (i * 512 + tid) * 16;
            uint4 v = *(const uint4*)(src + byt);
            int c = byt / ROWB;
            *(uint4*)(Bs + (byt ^ ((c & 7) << 4))) = v;
        }
    }
    __syncthreads();

    const int l = tid & 63;
    const int w = tid >> 6;
    const int rowg = w / CG;
    const int colb = (w % CG) * 128;
    const int lr = l & 15, lg = l >> 4;

    const int rowbase = blockIdx.x * (RG * 64) + rowg * 64;
    const int bb = rowbase / NNODES;
    const int n0 = rowbase - bb * NNODES;
    const size_t bbase = (size_t)bb * NNODES;

    unsigned soff[4], noff[4][4];
#pragma unroll
    for (int m = 0; m < 4; ++m) {
        int r = m * 16 + lr;
        soff[m] = (unsigned)(((rowbase + r) * (size_t)C + lg * 8) * sizeof(TIN));
        int4 nb = *(const int4*)(nbr + (size_t)(n0 + r) * 4);
        noff[m][0] = (unsigned)(((bbase + nb.x) * C + lg * 8) * sizeof(TIN));
        noff[m][1] = (unsigned)(((bbase + nb.y) * C + lg * 8) * sizeof(TIN));
        noff[m][2] = (unsigned)(((bbase + nb.z) * C + lg * 8) * sizeof(TIN));
        noff[m][3] = (unsigned)(((bbase + nb.w) * C + lg * 8) * sizeof(TIN));
    }
    const char* hb = (const char*)hin;

    f32x4 acc[4][8];
#pragma unroll
    for (int m = 0; m < 4; ++m)
#pragma unroll
        for (int j = 0; j < 8; ++j) acc[m][j] = (f32x4){0.f, 0.f, 0.f, 0.f};

#pragma unroll
    for (int kk = 0; kk < K2 / 32; ++kk) {
        const int k0 = kk * 32;
        short8 a[4];
        if (k0 < C) {
            const unsigned kb = k0 * sizeof(TIN);
#pragma unroll
            for (int m = 0; m < 4; ++m)
                a[m] = frag_self((const TIN*)(hb + soff[m] + kb));
        } else {
            const unsigned kb = (k0 - C) * sizeof(TIN);
#pragma unroll
            for (int m = 0; m < 4; ++m)
                a[m] = frag_mean4((const TIN*)(hb + noff[m][0] + kb),
                                  (const TIN*)(hb + noff[m][1] + kb),
                                  (const TIN*)(hb + noff[m][2] + kb),
                                  (const TIN*)(hb + noff[m][3] + kb));
        }
#pragma unroll
        for (int j = 0; j < 8; ++j) {
            const int c = colb + j * 16 + lr;
            const short8 bf = *(const short8*)(
                Bs + ((c * ROWB + (k0 + lg * 8) * 2) ^ ((l & 7) << 4)));
#pragma unroll
            for (int m = 0; m < 4; ++m)
                acc[m][j] = __builtin_amdgcn_mfma_f32_16x16x32_bf16(a[m], bf, acc[m][j], 0, 0, 0);
        }
    }

#pragma unroll
    for (int j = 0; j < 8; ++j) {
        const int gcol = gcol0 + colb + j * 16 + lr;
        const float bv = bias[gcol];
#pragma unroll
        for (int m = 0; m < 4; ++m) {
#pragma unroll
            for (int r = 0; r < 4; ++r) {
                const int row = rowbase + m * 16 + lg * 4 + r;
                storev(out + (size_t)row * DOUT + gcol, fmaxf(acc[m][j][r] + bv, 0.f));
            }
        }
    }
}

extern "C" void kernel_launch(void* const* d_in, const int* in_sizes, int n_in,
                              void* d_out, int out_size, void* d_ws, size_t ws_size,
                              hipStream_t stream) {
    const float* x = (const float*)d_in[0];
    const int* nbr = (const int*)d_in[1];
    const float* Ws1 = (const float*)d_in[2];
    const float* Wn1 = (const float*)d_in[3];
    const float* b1 = (const float*)d_in[4];
    const float* Ws2 = (const float*)d_in[5];
    const float* Wn2 = (const float*)d_in[6];
    const float* b2 = (const float*)d_in[7];
    float* out = (float*)d_out;

    const int B = in_sizes[0] / (NNODES * 128);  // 4
    const int M = B * NNODES;                    // 221184

    char* ws = (char*)d_ws;
    const size_t h1_bytes = (size_t)M * DOUT * 2;   // [M][256] bf16
    const size_t hm_bytes = (size_t)M * DOUT * 2;   // reused: hm1 [M][128] then hm2 [M][256]
    const size_t need = h1_bytes + hm_bytes + 131072 + 262144;

    if (ws_size >= need) {
        unsigned short* h1 = (unsigned short*)ws;
        unsigned short* hm = (unsigned short*)(ws + h1_bytes);
        unsigned short* Wt1 = (unsigned short*)(ws + h1_bytes + hm_bytes);
        unsigned short* Wt2 = Wt1 + 256 * 256;

        build_wt<<<256, 256, 0, stream>>>(Ws1, Wn1, Wt1, 128);
        build_wt<<<512, 256, 0, stream>>>(Ws2, Wn2, Wt2, 256);

        // layer 1: mean over x (f32) -> hm1 bf16; dense GEMM 256 cols (2 col-groups)
        mean_pass<128, float><<<M * 16 / 256, 256, 0, stream>>>(x, nbr, hm);
        sage_v4<128, float, unsigned short>
            <<<dim3(M / 256, 2), 512, 0, stream>>>(x, hm, Wt1, b1, h1);
        // layer 2: mean over h1 (bf16) -> hm2 bf16; dense GEMM (4 col-groups)
        mean_pass<256, unsigned short><<<M * 32 / 256, 256, 0, stream>>>(h1, nbr, hm);
        sage_v4<256, unsigned short, float>
            <<<dim3(M / 512, 4), 512, 0, stream>>>(h1, hm, Wt2, b2, out);
    } else {
        // fallback: round-3 fused kernels (ws needs only h1 + Wt)
        unsigned short* h1 = (unsigned short*)ws;
        unsigned short* Wt1 = (unsigned short*)(ws + h1_bytes);
        unsigned short* Wt2 = Wt1 + 256 * 256;

        build_wt<<<256, 256, 0, stream>>>(Ws1, Wn1, Wt1, 128);
        build_wt<<<512, 256, 0, stream>>>(Ws2, Wn2, Wt2, 256);

        hipFuncSetAttribute((const void*)sage_v3<128, float, unsigned short>,
                            hipFuncAttributeMaxDynamicSharedMemorySize, 131072);
        hipFuncSetAttribute((const void*)sage_v3<256, unsigned short, float>,
                            hipFuncAttributeMaxDynamicSharedMemorySize, 131072);

        sage_v3<128, float, unsigned short>
            <<<dim3(M / 256, 1), 512, 131072, stream>>>(x, nbr, Wt1, b1, h1);
        sage_v3<256, unsigned short, float>
            <<<dim3(M / 512, 2), 512, 131072, stream>>>(h1, nbr, Wt2, b2, out);
    }
}

// Round 5
// 422.412 us; speedup vs baseline: 1.0928x; 1.0928x over previous
//
#include <hip/hip_runtime.h>

typedef __attribute__((ext_vector_type(8))) short short8;
typedef __attribute__((ext_vector_type(4))) float f32x4;

#define NNODES 55296
#define DOUT 256

__device__ __forceinline__ float bf2f(unsigned short h) {
    union { unsigned u; float f; } x; x.u = ((unsigned)h) << 16; return x.f;
}
__device__ __forceinline__ unsigned short f2bf(float f) {
    union { float f; unsigned u; } x; x.f = f;
    return (unsigned short)((x.u + 0x7fffu + ((x.u >> 16) & 1u)) >> 16);
}

__device__ __forceinline__ void storev(float* p, float v) { *p = v; }
__device__ __forceinline__ void storev(unsigned short* p, float v) { *p = f2bf(v); }

// ---- fragment helpers ----
__device__ __forceinline__ short8 frag_self(const float* p) {
    float4 a = *(const float4*)p, b = *(const float4*)(p + 4);
    union { short8 s; unsigned short u[8]; } r;
    r.u[0] = f2bf(a.x); r.u[1] = f2bf(a.y); r.u[2] = f2bf(a.z); r.u[3] = f2bf(a.w);
    r.u[4] = f2bf(b.x); r.u[5] = f2bf(b.y); r.u[6] = f2bf(b.z); r.u[7] = f2bf(b.w);
    return r.s;
}
__device__ __forceinline__ short8 frag_self(const unsigned short* p) {
    return *(const short8*)p;
}
__device__ __forceinline__ void acc8(const float* p, float* o) {
    float4 a = *(const float4*)p, b = *(const float4*)(p + 4);
    o[0] += a.x; o[1] += a.y; o[2] += a.z; o[3] += a.w;
    o[4] += b.x; o[5] += b.y; o[6] += b.z; o[7] += b.w;
}
__device__ __forceinline__ void acc8(const unsigned short* p, float* o) {
    uint4 v = *(const uint4*)p;
    const unsigned short* u = (const unsigned short*)&v;
#pragma unroll
    for (int i = 0; i < 8; ++i) o[i] += bf2f(u[i]);
}
template <typename TIN>
__device__ __forceinline__ short8 frag_mean4(const TIN* p0, const TIN* p1,
                                             const TIN* p2, const TIN* p3) {
    float s[8] = {0.f, 0.f, 0.f, 0.f, 0.f, 0.f, 0.f, 0.f};
    acc8(p0, s); acc8(p1, s); acc8(p2, s); acc8(p3, s);
    union { short8 s8; unsigned short u[8]; } r;
#pragma unroll
    for (int i = 0; i < 8; ++i) r.u[i] = f2bf(s[i] * 0.25f);
    return r.s8;
}

// Wt[d][k] = bf16( k < C ? W_self[k][d] : W_neigh[k-C][d] )
__global__ void build_wt(const float* __restrict__ Ws,
                         const float* __restrict__ Wn,
                         unsigned short* __restrict__ Wt, int C) {
    int K2 = 2 * C;
    int idx = blockIdx.x * 256 + threadIdx.x;
    if (idx >= 256 * K2) return;
    int d = idx / K2;
    int k = idx - d * K2;
    float v = (k < C) ? Ws[(size_t)k * DOUT + d] : Wn[(size_t)(k - C) * DOUT + d];
    Wt[idx] = f2bf(v);
}

// ---- precompute hm[node][c] = bf16(mean of 4 neighbors) ----
template <int C, typename TIN>
__global__ __launch_bounds__(256) void mean_pass(const TIN* __restrict__ hin,
                                                 const int* __restrict__ nbr,
                                                 unsigned short* __restrict__ hm) {
    constexpr int CPL = C / 8;
    const int idx = blockIdx.x * 256 + threadIdx.x;
    const int node = idx / CPL;
    const int ch = (idx - node * CPL) * 8;
    const int b = node / NNODES;
    const int n = node - b * NNODES;
    const size_t bbase = (size_t)b * NNODES;
    const int4 nb = *(const int4*)(nbr + (size_t)n * 4);
    float s[8] = {0.f, 0.f, 0.f, 0.f, 0.f, 0.f, 0.f, 0.f};
    acc8(hin + (bbase + nb.x) * (size_t)C + ch, s);
    acc8(hin + (bbase + nb.y) * (size_t)C + ch, s);
    acc8(hin + (bbase + nb.z) * (size_t)C + ch, s);
    acc8(hin + (bbase + nb.w) * (size_t)C + ch, s);
    union { uint4 v; unsigned short u[8]; } r;
#pragma unroll
    for (int i = 0; i < 8; ++i) r.u[i] = f2bf(s[i] * 0.25f);
    *(uint4*)(hm + (size_t)node * C + ch) = r.v;
}

// ---- v5: weights in 128KB dynamic LDS (1 block/CU, 256-reg budget),
// dense A (self | precomputed mean), depth-D register prefetch pipeline.
// Layer1: all 256 cols per block (A read once). Layer2: 128 cols, y-paired.
template <int C, typename TIN, typename TOUT>
__global__ __launch_bounds__(512, 2) void sage_v5(
    const TIN* __restrict__ hin,              // [M][C]
    const unsigned short* __restrict__ hm,    // [M][C] bf16
    const unsigned short* __restrict__ Wt,    // [256][2C] bf16, d-major
    const float* __restrict__ bias,           // [256]
    TOUT* __restrict__ out) {                 // [M][256]
    constexpr int K2 = 2 * C;
    constexpr int ROWB = K2 * 2;              // bytes per Wt row (512 / 1024)
    constexpr int LCOLS = 131072 / ROWB;      // 256 (L1) / 128 (L2)
    constexpr int CG = LCOLS / 64;            // wave col-groups: 4 / 2
    constexpr int RG = 8 / CG;                // wave row-groups: 2 / 4
    constexpr int CGRID = 256 / LCOLS;        // grid col splits: 1 / 2
    constexpr int NK = K2 / 32;               // 8 / 16
    constexpr int D = (sizeof(TIN) == 4) ? 3 : 4;  // prefetch depth
    extern __shared__ char Bs[];              // 128 KB

    const int tid = threadIdx.x;
    const int bid = blockIdx.x;
    const int yg = bid % CGRID;               // col-group (adjacent blocks pair)
    const int rb = bid / CGRID;
    const int gcol0 = yg * LCOLS;

    // ---- stage weights (128KB), XOR-swizzled by (col&7)<<4 ----
    {
        const char* src = (const char*)(Wt + (size_t)gcol0 * K2);
#pragma unroll
        for (int i = 0; i < 16; ++i) {
            int byt = (i * 512 + tid) * 16;
            uint4 v = *(const uint4*)(src + byt);
            int c = byt / ROWB;
            *(uint4*)(Bs + (byt ^ ((c & 7) << 4))) = v;
        }
    }
    __syncthreads();

    const int l = tid & 63;
    const int w = tid >> 6;
    const int rowg = w / CG;
    const int colb = (w % CG) * 64;
    const int lr = l & 15, lg = l >> 4;

    const int rowbase = rb * (RG * 64) + rowg * 64;
    const char* hb = (const char*)hin;
    const char* hmb = (const char*)hm;

    unsigned sofs[4], mofs[4];
#pragma unroll
    for (int m = 0; m < 4; ++m) {
        const int r = rowbase + m * 16 + lr;
        sofs[m] = (unsigned)(((size_t)r * C + lg * 8) * sizeof(TIN));
        mofs[m] = (unsigned)(((size_t)r * C + lg * 8) * 2);
    }

    f32x4 acc[4][4];
#pragma unroll
    for (int m = 0; m < 4; ++m)
#pragma unroll
        for (int j = 0; j < 4; ++j) acc[m][j] = (f32x4){0.f, 0.f, 0.f, 0.f};

    auto loadA = [&](int kk, short8* a) {
        const int k0 = kk * 32;
        if (k0 < C) {
#pragma unroll
            for (int m = 0; m < 4; ++m)
                a[m] = frag_self((const TIN*)(hb + sofs[m] + (unsigned)k0 * sizeof(TIN)));
        } else {
#pragma unroll
            for (int m = 0; m < 4; ++m)
                a[m] = *(const short8*)(hmb + mofs[m] + (unsigned)(k0 - C) * 2);
        }
    };

    short8 ab[D][4];
#pragma unroll
    for (int p = 0; p < D; ++p) loadA(p, ab[p]);

#pragma unroll
    for (int kk = 0; kk < NK; ++kk) {
        const int k0 = kk * 32;
        short8 cur[4];
#pragma unroll
        for (int m = 0; m < 4; ++m) cur[m] = ab[kk % D][m];
        if (kk + D < NK) loadA(kk + D, ab[kk % D]);
#pragma unroll
        for (int j = 0; j < 4; ++j) {
            const int c = colb + j * 16 + lr;
            const short8 bf = *(const short8*)(
                Bs + ((c * ROWB + (k0 + lg * 8) * 2) ^ ((l & 7) << 4)));
#pragma unroll
            for (int m = 0; m < 4; ++m)
                acc[m][j] = __builtin_amdgcn_mfma_f32_16x16x32_bf16(cur[m], bf, acc[m][j], 0, 0, 0);
        }
    }

#pragma unroll
    for (int j = 0; j < 4; ++j) {
        const int gcol = gcol0 + colb + j * 16 + lr;
        const float bv = bias[gcol];
#pragma unroll
        for (int m = 0; m < 4; ++m) {
#pragma unroll
            for (int r = 0; r < 4; ++r) {
                const int row = rowbase + m * 16 + lg * 4 + r;
                storev(out + (size_t)row * DOUT + gcol, fmaxf(acc[m][j][r] + bv, 0.f));
            }
        }
    }
}

// ---- v3 (round-3 kernel), fallback when ws is too small for mean buffers ----
template <int C, typename TIN, typename TOUT>
__global__ __launch_bounds__(512, 2) void sage_v3(
    const TIN* __restrict__ hin, const int* __restrict__ nbr,
    const unsigned short* __restrict__ Wt, const float* __restrict__ bias,
    TOUT* __restrict__ out) {
    constexpr int K2 = 2 * C;
    constexpr int ROWB = K2 * 2;
    constexpr int LCOLS = 131072 / ROWB;
    constexpr int CG = LCOLS / 128;
    constexpr int RG = 8 / CG;
    extern __shared__ char Bs[];

    const int tid = threadIdx.x;
    const int gcol0 = blockIdx.y * LCOLS;
    {
        const char* src = (const char*)(Wt + (size_t)gcol0 * K2);
#pragma unroll
        for (int i = 0; i < 16; ++i) {
            int byt = (i * 512 + tid) * 16;
            uint4 v = *(const uint4*)(src + byt);
            int c = byt / ROWB;
            *(uint4*)(Bs + (byt ^ ((c & 7) << 4))) = v;
        }
    }
    __syncthreads();

    const int l = tid & 63;
    const int w = tid >> 6;
    const int rowg = w / CG;
    const int colb = (w % CG) * 128;
    const int lr = l & 15, lg = l >> 4;

    const int rowbase = blockIdx.x * (RG * 64) + rowg * 64;
    const int bb = rowbase / NNODES;
    const int n0 = rowbase - bb * NNODES;
    const size_t bbase = (size_t)bb * NNODES;

    unsigned soff[4], noff[4][4];
#pragma unroll
    for (int m = 0; m < 4; ++m) {
        int r = m * 16 + lr;
        soff[m] = (unsigned)(((rowbase + r) * (size_t)C + lg * 8) * sizeof(TIN));
        int4 nb = *(const int4*)(nbr + (size_t)(n0 + r) * 4);
        noff[m][0] = (unsigned)(((bbase + nb.x) * C + lg * 8) * sizeof(TIN));
        noff[m][1] = (unsigned)(((bbase + nb.y) * C + lg * 8) * sizeof(TIN));
        noff[m][2] = (unsigned)(((bbase + nb.z) * C + lg * 8) * sizeof(TIN));
        noff[m][3] = (unsigned)(((bbase + nb.w) * C + lg * 8) * sizeof(TIN));
    }
    const char* hb = (const char*)hin;

    f32x4 acc[4][8];
#pragma unroll
    for (int m = 0; m < 4; ++m)
#pragma unroll
        for (int j = 0; j < 8; ++j) acc[m][j] = (f32x4){0.f, 0.f, 0.f, 0.f};

#pragma unroll
    for (int kk = 0; kk < K2 / 32; ++kk) {
        const int k0 = kk * 32;
        short8 a[4];
        if (k0 < C) {
            const unsigned kb = k0 * sizeof(TIN);
#pragma unroll
            for (int m = 0; m < 4; ++m)
                a[m] = frag_self((const TIN*)(hb + soff[m] + kb));
        } else {
            const unsigned kb = (k0 - C) * sizeof(TIN);
#pragma unroll
            for (int m = 0; m < 4; ++m)
                a[m] = frag_mean4((const TIN*)(hb + noff[m][0] + kb),
                                  (const TIN*)(hb + noff[m][1] + kb),
                                  (const TIN*)(hb + noff[m][2] + kb),
                                  (const TIN*)(hb + noff[m][3] + kb));
        }
#pragma unroll
        for (int j = 0; j < 8; ++j) {
            const int c = colb + j * 16 + lr;
            const short8 bf = *(const short8*)(
                Bs + ((c * ROWB + (k0 + lg * 8) * 2) ^ ((l & 7) << 4)));
#pragma unroll
            for (int m = 0; m < 4; ++m)
                acc[m][j] = __builtin_amdgcn_mfma_f32_16x16x32_bf16(a[m], bf, acc[m][j], 0, 0, 0);
        }
    }

#pragma unroll
    for (int j = 0; j < 8; ++j) {
        const int gcol = gcol0 + colb + j * 16 + lr;
        const float bv = bias[gcol];
#pragma unroll
        for (int m = 0; m < 4; ++m) {
#pragma unroll
            for (int r = 0; r < 4; ++r) {
                const int row = rowbase + m * 16 + lg * 4 + r;
                storev(out + (size_t)row * DOUT + gcol, fmaxf(acc[m][j][r] + bv, 0.f));
            }
        }
    }
}

extern "C" void kernel_launch(void* const* d_in, const int* in_sizes, int n_in,
                              void* d_out, int out_size, void* d_ws, size_t ws_size,
                              hipStream_t stream) {
    const float* x = (const float*)d_in[0];
    const int* nbr = (const int*)d_in[1];
    const float* Ws1 = (const float*)d_in[2];
    const float* Wn1 = (const float*)d_in[3];
    const float* b1 = (const float*)d_in[4];
    const float* Ws2 = (const float*)d_in[5];
    const float* Wn2 = (const float*)d_in[6];
    const float* b2 = (const float*)d_in[7];
    float* out = (float*)d_out;

    const int B = in_sizes[0] / (NNODES * 128);  // 4
    const int M = B * NNODES;                    // 221184

    char* ws = (char*)d_ws;
    const size_t h1_bytes = (size_t)M * DOUT * 2;
    const size_t hm_bytes = (size_t)M * DOUT * 2;
    const size_t need = h1_bytes + hm_bytes + 131072 + 262144;

    if (ws_size >= need) {
        unsigned short* h1 = (unsigned short*)ws;
        unsigned short* hm = (unsigned short*)(ws + h1_bytes);
        unsigned short* Wt1 = (unsigned short*)(ws + h1_bytes + hm_bytes);
        unsigned short* Wt2 = Wt1 + 256 * 256;

        build_wt<<<256, 256, 0, stream>>>(Ws1, Wn1, Wt1, 128);
        build_wt<<<512, 256, 0, stream>>>(Ws2, Wn2, Wt2, 256);

        hipFuncSetAttribute((const void*)sage_v5<128, float, unsigned short>,
                            hipFuncAttributeMaxDynamicSharedMemorySize, 131072);
        hipFuncSetAttribute((const void*)sage_v5<256, unsigned short, float>,
                            hipFuncAttributeMaxDynamicSharedMemorySize, 131072);

        // layer 1: block = 128 rows x 256 cols (all cols; A read once)
        mean_pass<128, float><<<M * 16 / 256, 256, 0, stream>>>(x, nbr, hm);
        sage_v5<128, float, unsigned short>
            <<<M / 128, 512, 131072, stream>>>(x, hm, Wt1, b1, h1);
        // layer 2: block = 256 rows x 128 cols, col-pairs adjacent in grid
        mean_pass<256, unsigned short><<<M * 32 / 256, 256, 0, stream>>>(h1, nbr, hm);
        sage_v5<256, unsigned short, float>
            <<<(M / 256) * 2, 512, 131072, stream>>>(h1, hm, Wt2, b2, out);
    } else {
        unsigned short* h1 = (unsigned short*)ws;
        unsigned short* Wt1 = (unsigned short*)(ws + h1_bytes);
        unsigned short* Wt2 = Wt1 + 256 * 256;

        build_wt<<<256, 256, 0, stream>>>(Ws1, Wn1, Wt1, 128);
        build_wt<<<512, 256, 0, stream>>>(Ws2, Wn2, Wt2, 256);

        hipFuncSetAttribute((const void*)sage_v3<128, float, unsigned short>,
                            hipFuncAttributeMaxDynamicSharedMemorySize, 131072);
        hipFuncSetAttribute((const void*)sage_v3<256, unsigned short, float>,
                            hipFuncAttributeMaxDynamicSharedMemorySize, 131072);

        sage_v3<128, float, unsigned short>
            <<<dim3(M / 256, 1), 512, 131072, stream>>>(x, nbr, Wt1, b1, h1);
        sage_v3<256, unsigned short, float>
            <<<dim3(M / 512, 2), 512, 131072, stream>>>(h1, nbr, Wt2, b2, out);
    }
}